// Round 6
// baseline (559.895 us; speedup 1.0000x reference)
//
#include <hip/hip_runtime.h>

typedef unsigned short u16;
typedef __attribute__((ext_vector_type(8))) short short8;
typedef __attribute__((ext_vector_type(4))) float f32x4;

__device__ __forceinline__ float bf2f(u16 u){ return __uint_as_float(((unsigned)u)<<16); }
__device__ __forceinline__ u16 f2bf(float f){
  unsigned u = __float_as_uint(f);
  unsigned r = u + 0x7fffu + ((u>>16)&1u);   // RNE (no NaN/inf in this problem)
  return (u16)(r>>16);
}

#define MFMA16(a,b,c) __builtin_amdgcn_mfma_f32_16x16x32_bf16(a,b,c,0,0,0)

// ---- attn LDS layout (u16 offsets). Strides 264/72 (16B-aligned rows, 2-way
// bank aliasing on b128 fragment reads = free per m136).
static constexpr int XS_STR  = 264;
static constexpr int PS_STR  = 72;
static constexpr int WT_STR  = 72;
static constexpr int XHI_OFF = 0;         // 64x264
static constexpr int XLO_OFF = 16896;
static constexpr int GT_OFF  = 33792;     // 64x264, Ghi then Glo per head
static constexpr int XVT_OFF = 50688;     // 256x72, persistent Xv^T
static constexpr int PS_OFF  = 69120;     // 64x72
static constexpr int SMRE_OFF= 73728;     // 64 rows x 2 halves x (mx,sum) f32
static constexpr int SMEM_BYTES = (73728 + 512)*2;   // 148480 B

// ---- mh LDS
static constexpr int MH_SMEM = 70656*2;   // Qhi/Qlo 64x264 + Chi/Clo 256x72

// ---- ws layout (u16): mhi[524288] | mlo[524288] | khi[65536] | klo[65536]
//                       | vT[65536] | soP[4096 u16 = 2048 f32]   (~2.38 MB)

// prep: 0..63 ksplit | 64..79 vT | 80..335 so | 336..847 zero out
__global__ void prep_kernel(const float* __restrict__ k, const float* __restrict__ v,
                            const float* __restrict__ o, u16* __restrict__ khi,
                            u16* __restrict__ klo, u16* __restrict__ vT,
                            float* __restrict__ soP, float4* __restrict__ outz){
  __shared__ float Ts[64*65];
  const int blk = blockIdx.x, tid = threadIdx.x;
  if (blk < 64){
    int base = blk*1024 + tid*4;
    const float4 f4 = *(const float4*)(k + base);
    ushort4 hv, lv;
    hv.x=f2bf(f4.x); lv.x=f2bf(f4.x-bf2f(hv.x));
    hv.y=f2bf(f4.y); lv.y=f2bf(f4.y-bf2f(hv.y));
    hv.z=f2bf(f4.z); lv.z=f2bf(f4.z-bf2f(hv.z));
    hv.w=f2bf(f4.w); lv.w=f2bf(f4.w-bf2f(hv.w));
    *(ushort4*)&khi[base] = hv;
    *(ushort4*)&klo[base] = lv;
  } else if (blk < 80){
    int t = blk - 64;
    const int bi = (t>>2)<<6, bj = (t&3)<<6;
    #pragma unroll
    for (int p=0;p<4;p++){
      int idx4 = tid + (p<<8);
      int i = idx4 >> 4, c4 = (idx4 & 15) << 2;
      const float4 f4 = *(const float4*)(v + ((bi+i)<<8) + bj + c4);
      Ts[i*65+c4]=f4.x; Ts[i*65+c4+1]=f4.y; Ts[i*65+c4+2]=f4.z; Ts[i*65+c4+3]=f4.w;
    }
    __syncthreads();
    #pragma unroll
    for (int p=0;p<2;p++){
      int ch = tid + (p<<8);
      int j = ch >> 3, i8 = (ch & 7) << 3;
      short8 t8;
      #pragma unroll
      for (int e=0;e<8;e++) t8[e] = (short)f2bf(Ts[(i8+e)*65 + j]);
      *(short8*)&vT[((bj+j)<<8) + bi + i8] = t8;
    }
  } else if (blk < 336){
    int p = blk - 80;                      // 256 blocks: 8 h x 32 chunks of 8 rows
    int h = p >> 5, base = (p & 31) << 3;
    int w = tid >> 6, l = tid & 63;
    #pragma unroll
    for (int i=0;i<2;i++){
      int row = base + w*2 + i;
      const float4 f4 = *(const float4*)(o + (((h<<8)+row)<<8) + (l<<2));
      float s = f4.x + f4.y + f4.z + f4.w;
      #pragma unroll
      for (int off=32; off>=1; off>>=1) s += __shfl_xor(s, off, 64);
      if (l==0) soP[(h<<8)+row] = s;
    }
  } else {
    int z = blk - 336;                     // 512 blocks x 4096 float4
    const float4 zf4 = {0.f,0.f,0.f,0.f};
    #pragma unroll
    for (int i=0;i<16;i++) outz[z*4096 + i*256 + tid] = zf4;
  }
}

// MhT[h][dp][d] = sum_ko q[h][d][ko]*k[dp][ko], hi/lo bf16 via 3-term MFMA
__global__ __launch_bounds__(256,1) void mh_kernel(
    const float* __restrict__ q, const u16* __restrict__ khi,
    const u16* __restrict__ klo, u16* __restrict__ mhi, u16* __restrict__ mlo)
{
  extern __shared__ u16 sm[];
  u16* Qhi = sm;
  u16* Qlo = sm + 16896;
  u16* Chi = sm + 33792;
  u16* Clo = sm + 52224;

  const int tid = threadIdx.x;
  const int w = tid >> 6, lane = tid & 63;
  const int quad = lane >> 4, m16 = lane & 15;
  const int cw = w << 6, koq = quad << 3;
  const int h = blockIdx.x >> 2, dt = (blockIdx.x & 3) << 6;

  #pragma unroll
  for (int i=0;i<16;i++){
    int idx4 = i*256 + tid;
    int tr = idx4 >> 6, c4 = (idx4 & 63) << 2;
    const float4 xv = *(const float4*)(q + (((h<<8)+dt+tr)<<8) + c4);
    ushort4 hv, lv;
    hv.x=f2bf(xv.x); lv.x=f2bf(xv.x-bf2f(hv.x));
    hv.y=f2bf(xv.y); lv.y=f2bf(xv.y-bf2f(hv.y));
    hv.z=f2bf(xv.z); lv.z=f2bf(xv.z-bf2f(hv.z));
    hv.w=f2bf(xv.w); lv.w=f2bf(xv.w-bf2f(hv.w));
    *(ushort4*)&Qhi[tr*XS_STR + c4] = hv;
    *(ushort4*)&Qlo[tr*XS_STR + c4] = lv;
  }
  __syncthreads();

  const f32x4 zf = {0.f,0.f,0.f,0.f};
  f32x4 acc[4][4];
  #pragma unroll
  for (int r=0;r<4;r++)
    #pragma unroll
    for (int c=0;c<4;c++) acc[r][c] = zf;

  #pragma unroll
  for (int kk=0;kk<8;kk++){
    const int ko = (kk<<5) + koq;
    short8 Ah[4], Al[4], Bh[4], Bl[4];
    #pragma unroll
    for (int c=0;c<4;c++){
      Bh[c] = *(const short8*)&khi[(cw + c*16 + m16)*256 + ko];
      Bl[c] = *(const short8*)&klo[(cw + c*16 + m16)*256 + ko];
    }
    #pragma unroll
    for (int r=0;r<4;r++) Ah[r] = *(const short8*)&Qhi[(r*16+m16)*XS_STR + ko];
    #pragma unroll
    for (int r=0;r<4;r++) Al[r] = *(const short8*)&Qlo[(r*16+m16)*XS_STR + ko];
    #pragma unroll
    for (int r=0;r<4;r++)
      #pragma unroll
      for (int c=0;c<4;c++){
        acc[r][c] = MFMA16(Ah[r], Bh[c], acc[r][c]);
        acc[r][c] = MFMA16(Ah[r], Bl[c], acc[r][c]);
        acc[r][c] = MFMA16(Al[r], Bh[c], acc[r][c]);
      }
  }

  #pragma unroll
  for (int r=0;r<4;r++)
    #pragma unroll
    for (int c=0;c<4;c++)
      #pragma unroll
      for (int g=0; g<4; g++){
        int drow = r*16 + quad*4 + g;
        int dp   = cw + c*16 + m16;
        float vv = acc[r][c][g];
        u16 hh = f2bf(vv);
        Chi[dp*WT_STR + drow] = hh;
        Clo[dp*WT_STR + drow] = f2bf(vv - bf2f(hh));
      }
  __syncthreads();

  #pragma unroll
  for (int p=0;p<8;p++){
    int ch = tid + (p<<8);
    int dp = ch >> 3, i8 = (ch & 7) << 3;
    *(int4*)&mhi[(((h<<8)+dp)<<8) + dt + i8] = *(const int4*)&Chi[dp*WT_STR + i8];
    *(int4*)&mlo[(((h<<8)+dp)<<8) + dt + i8] = *(const int4*)&Clo[dp*WT_STR + i8];
  }
}

// Merged attention: blocks [0,512) branch 0 (per-(b,y), heads 0..3),
// [512,1024) branch 1 (per-(b,x), heads 4..7). out pre-zeroed; atomicAdd.
// 8 waves: mm3/Xv/Y split 2rt x 4ct; logits split 16-row x 32-z.
__global__ __launch_bounds__(512,2) void attn_kernel(
    const float* __restrict__ x, const u16* __restrict__ mhiP,
    const u16* __restrict__ mloP, const u16* __restrict__ vT,
    const float* __restrict__ soP, float* __restrict__ out)
{
  extern __shared__ u16 sm[];
  u16* Xhi = sm + XHI_OFF;
  u16* Xlo = sm + XLO_OFF;
  u16* Gt  = sm + GT_OFF;
  u16* Xvt = sm + XVT_OFF;
  u16* Ps  = sm + PS_OFF;
  float* SMf = (float*)(sm + SMRE_OFF);   // [row][half][mx,sum]

  const int tid  = threadIdx.x;
  const int w    = tid >> 6, lane = tid & 63;
  const int quad = lane >> 4, m16 = lane & 15;
  const int br   = blockIdx.x >> 9;
  const int idx  = blockIdx.x & 511;
  const int b    = idx >> 6, s = idx & 63;
  const int rtb  = (w & 1) << 1;      // rowtile base: rows rtb*16 .. rtb*16+31
  const int cwb  = (w >> 1) << 6;     // 4 coltiles
  const int rs   = (w >> 1) << 4;     // logits: 16-row strip
  const int zh   = w & 1;             // logits: z half
  const int koq  = quad << 3;

  auto tok = [&](int t)->int {
    int m = br ? s : t;
    int n = br ? t : s;
    return (((b<<6) + m) << 14) + (n << 8);
  };

  // ---- stage X hi/lo
  #pragma unroll
  for (int i=0;i<8;i++){
    int idx4 = i*512 + tid;
    int tr = idx4 >> 6, c4 = (idx4 & 63) << 2;
    const float4 xv = *(const float4*)(x + tok(tr) + c4);
    ushort4 hv, lv;
    hv.x=f2bf(xv.x); lv.x=f2bf(xv.x-bf2f(hv.x));
    hv.y=f2bf(xv.y); lv.y=f2bf(xv.y-bf2f(hv.y));
    hv.z=f2bf(xv.z); lv.z=f2bf(xv.z-bf2f(hv.z));
    hv.w=f2bf(xv.w); lv.w=f2bf(xv.w-bf2f(hv.w));
    *(ushort4*)&Xhi[tr*XS_STR + c4] = hv;
    *(ushort4*)&Xlo[tr*XS_STR + c4] = lv;
  }
  __syncthreads();

  // ---- persist logits B-side Xhi fragments (constant across heads)
  short8 XB[16];
  #pragma unroll
  for (int kk=0;kk<8;kk++)
    #pragma unroll
    for (int c=0;c<2;c++)
      XB[kk*2+c] = *(const short8*)&Xhi[((zh<<5) + c*16 + m16)*XS_STR + (kk<<5) + koq];

  const f32x4 zf = {0.f,0.f,0.f,0.f};
  f32x4 acc[2][4];

  // acc = Xhi@Whi + Xhi@Wlo + Xlo@Whi over 2 rowtiles x 4 coltiles
  auto mm3 = [&](const u16* __restrict__ Whi, const u16* __restrict__ Wlo){
    #pragma unroll
    for (int r=0;r<2;r++)
      #pragma unroll
      for (int c=0;c<4;c++) acc[r][c] = zf;
    #pragma unroll
    for (int kk=0;kk<8;kk++){
      const int ko = (kk<<5) + koq;
      short8 Ah[2], Al[2], Bh[4], Bl[4];
      #pragma unroll
      for (int c=0;c<4;c++){
        Bh[c] = *(const short8*)&Whi[(cwb + c*16 + m16)*256 + ko];
        Bl[c] = *(const short8*)&Wlo[(cwb + c*16 + m16)*256 + ko];
      }
      #pragma unroll
      for (int r=0;r<2;r++){
        Ah[r] = *(const short8*)&Xhi[((rtb+r)*16+m16)*XS_STR + ko];
        Al[r] = *(const short8*)&Xlo[((rtb+r)*16+m16)*XS_STR + ko];
      }
      #pragma unroll
      for (int r=0;r<2;r++)
        #pragma unroll
        for (int c=0;c<4;c++){
          acc[r][c] = MFMA16(Ah[r], Bh[c], acc[r][c]);
          acc[r][c] = MFMA16(Ah[r], Bl[c], acc[r][c]);
          acc[r][c] = MFMA16(Al[r], Bh[c], acc[r][c]);
        }
    }
  };

  // ---- Xv = Xhi @ vT over 2rt x 4ct; store Xv^T (unscaled) in LDS
  {
    #pragma unroll
    for (int r=0;r<2;r++)
      #pragma unroll
      for (int c=0;c<4;c++) acc[r][c] = zf;
    #pragma unroll
    for (int kk=0;kk<8;kk++){
      const int ko = (kk<<5) + koq;
      short8 A[2], Bf[4];
      #pragma unroll
      for (int c=0;c<4;c++) Bf[c] = *(const short8*)&vT[(cwb + c*16 + m16)*256 + ko];
      #pragma unroll
      for (int r=0;r<2;r++) A[r] = *(const short8*)&Xhi[((rtb+r)*16+m16)*XS_STR + ko];
      #pragma unroll
      for (int r=0;r<2;r++)
        #pragma unroll
        for (int c=0;c<4;c++) acc[r][c] = MFMA16(A[r], Bf[c], acc[r][c]);
    }
    #pragma unroll
    for (int r=0;r<2;r++)
      #pragma unroll
      for (int c=0;c<4;c++)
        #pragma unroll
        for (int g=0; g<4; g++){
          int z  = (rtb+r)*16 + quad*4 + g;
          int vc = cwb + c*16 + m16;
          Xvt[vc*WT_STR + z] = f2bf(acc[r][c][g]);
        }
    // visible to other waves after bar1 of head 0
  }

  f32x4 Z[2][4];
  #pragma unroll
  for (int r=0;r<2;r++)
    #pragma unroll
    for (int c=0;c<4;c++) Z[r][c] = zf;

  for (int h=0; h<4; h++){
    const int gh = br*4 + h;

    // ---- G = X @ Mh[gh] (3-term hi/lo); write Ghi
    mm3(mhiP + gh*65536, mloP + gh*65536);
    #pragma unroll
    for (int r=0;r<2;r++)
      #pragma unroll
      for (int c=0;c<4;c++)
        #pragma unroll
        for (int g=0; g<4; g++){
          int row = (rtb+r)*16 + quad*4 + g;
          int col = cwb + c*16 + m16;
          Gt[row*XS_STR + col] = f2bf(acc[r][c][g]);
        }
    __syncthreads();                       // bar1: Ghi (+Xvt at h==0) visible

    // ---- logits A: Ghi@Xhi^T (regs) + Ghi@Xlo^T. Rows rs..rs+16, z half zh.
    f32x4 L[2];
    L[0] = zf; L[1] = zf;
    #pragma unroll
    for (int kk=0;kk<8;kk++){
      const int ko = (kk<<5) + koq;
      short8 A = *(const short8*)&Gt[(rs+m16)*XS_STR + ko];
      #pragma unroll
      for (int c=0;c<2;c++){
        L[c] = MFMA16(A, XB[kk*2+c], L[c]);
        short8 Bl = *(const short8*)&Xlo[((zh<<5) + c*16 + m16)*XS_STR + ko];
        L[c] = MFMA16(A, Bl, L[c]);
      }
    }
    __syncthreads();                       // bar2: Gt-hi reads done -> overwrite
    #pragma unroll
    for (int r=0;r<2;r++)
      #pragma unroll
      for (int c=0;c<4;c++)
        #pragma unroll
        for (int g=0; g<4; g++){
          int row = (rtb+r)*16 + quad*4 + g;
          int col = cwb + c*16 + m16;
          float vv = acc[r][c][g];
          u16 hh = f2bf(vv);
          Gt[row*XS_STR + col] = f2bf(vv - bf2f(hh));   // Glo
        }
    __syncthreads();                       // bar3: Glo visible

    // ---- logits B: Glo@Xhi^T (regs)
    #pragma unroll
    for (int kk=0;kk<8;kk++){
      const int ko = (kk<<5) + koq;
      short8 A = *(const short8*)&Gt[(rs+m16)*XS_STR + ko];
      #pragma unroll
      for (int c=0;c<2;c++)
        L[c] = MFMA16(A, XB[kk*2+c], L[c]);
    }

    // ---- softmax: local (32-z half) max/sum, cross-wave merge via SMf
    float mxl[4], sml[4];
    #pragma unroll
    for (int g=0; g<4; g++){
      float mx = fmaxf(L[0][g], L[1][g]);
      #pragma unroll
      for (int off=1; off<16; off<<=1) mx = fmaxf(mx, __shfl_xor(mx, off, 64));
      float sum = 0.f;
      #pragma unroll
      for (int c=0;c<2;c++){ float e = __expf(L[c][g]-mx); L[c][g] = e; sum += e; }
      #pragma unroll
      for (int off=1; off<16; off<<=1) sum += __shfl_xor(sum, off, 64);
      mxl[g] = mx; sml[g] = sum;
      if (m16 == 0){
        int row = rs + quad*4 + g;
        SMf[row*4 + zh*2]     = mx;
        SMf[row*4 + zh*2 + 1] = sum;
      }
    }
    __syncthreads();                       // bar4: SMf visible
    #pragma unroll
    for (int g=0; g<4; g++){
      int row = rs + quad*4 + g;
      float mxo = SMf[row*4 + (zh^1)*2];
      float smo = SMf[row*4 + (zh^1)*2 + 1];
      float M   = fmaxf(mxl[g], mxo);
      float al  = __expf(mxl[g]-M), ao = __expf(mxo-M);
      float scale = al / (sml[g]*al + smo*ao);
      #pragma unroll
      for (int c=0;c<2;c++)
        Ps[row*PS_STR + (zh<<5) + c*16 + m16] = f2bf(L[c][g]*scale);
    }
    __syncthreads();                       // bar5: Ps visible

    // ---- Y = P @ Xv over 2rt x 4ct; Z += so * Y
    #pragma unroll
    for (int r=0;r<2;r++)
      #pragma unroll
      for (int c=0;c<4;c++) acc[r][c] = zf;
    #pragma unroll
    for (int kk=0;kk<2;kk++){
      const int ko = (kk<<5) + koq;
      short8 A[2], Bf[4];
      #pragma unroll
      for (int c=0;c<4;c++) Bf[c] = *(const short8*)&Xvt[(cwb + c*16 + m16)*WT_STR + ko];
      #pragma unroll
      for (int r=0;r<2;r++) A[r] = *(const short8*)&Ps[((rtb+r)*16+m16)*PS_STR + ko];
      #pragma unroll
      for (int r=0;r<2;r++)
        #pragma unroll
        for (int c=0;c<4;c++) acc[r][c] = MFMA16(A[r], Bf[c], acc[r][c]);
    }
    float sc[4];
    #pragma unroll
    for (int c=0;c<4;c++) sc[c] = soP[gh*256 + cwb + c*16 + m16];
    #pragma unroll
    for (int r=0;r<2;r++)
      #pragma unroll
      for (int c=0;c<4;c++)
        #pragma unroll
        for (int g=0; g<4; g++) Z[r][c][g] += sc[c]*acc[r][c][g];
    // no trailing barrier: head h+1's Gt writes precede its bar1; all Gt/Ps/SMf
    // reads of head h complete before bar4/bar5 of head h.
  }

  // ---- epilogue: atomic accumulate into pre-zeroed out
  #pragma unroll
  for (int r=0;r<2;r++)
    #pragma unroll
    for (int c=0;c<4;c++)
      #pragma unroll
      for (int g=0; g<4; g++){
        int t   = (rtb+r)*16 + quad*4 + g;
        int col = cwb + c*16 + m16;
        atomicAdd(&out[tok(t) + col], Z[r][c][g]);
      }
}

extern "C" void kernel_launch(void* const* d_in, const int* in_sizes, int n_in,
                              void* d_out, int out_size, void* d_ws, size_t ws_size,
                              hipStream_t stream) {
  const float* x = (const float*)d_in[0];
  const float* q = (const float*)d_in[1];
  const float* k = (const float*)d_in[2];
  const float* v = (const float*)d_in[3];
  const float* o = (const float*)d_in[4];
  u16* ws   = (u16*)d_ws;                    // ~2.38 MB
  u16* mhi  = ws;
  u16* mlo  = ws + 524288;
  u16* khi  = ws + 1048576;
  u16* klo  = ws + 1114112;
  u16* vT   = ws + 1179648;
  float* soP = (float*)(ws + 1245184);
  float* out = (float*)d_out;

  prep_kernel<<<848, 256, 0, stream>>>(k, v, o, khi, klo, vT, soP, (float4*)d_out);
  (void)hipFuncSetAttribute(reinterpret_cast<const void*>(&mh_kernel),
                            hipFuncAttributeMaxDynamicSharedMemorySize, MH_SMEM);
  mh_kernel<<<32, 256, MH_SMEM, stream>>>(q, khi, klo, mhi, mlo);

  (void)hipFuncSetAttribute(reinterpret_cast<const void*>(&attn_kernel),
                            hipFuncAttributeMaxDynamicSharedMemorySize, SMEM_BYTES);
  attn_kernel<<<1024, 512, SMEM_BYTES, stream>>>(x, mhi, mlo, vT, soP, out);
}

// Round 7
// 341.358 us; speedup vs baseline: 1.6402x; 1.6402x over previous
//
#include <hip/hip_runtime.h>

typedef unsigned short u16;
typedef __attribute__((ext_vector_type(8))) short short8;
typedef __attribute__((ext_vector_type(4))) float f32x4;

__device__ __forceinline__ float bf2f(u16 u){ return __uint_as_float(((unsigned)u)<<16); }
__device__ __forceinline__ u16 f2bf(float f){
  unsigned u = __float_as_uint(f);
  unsigned r = u + 0x7fffu + ((u>>16)&1u);   // RNE (no NaN/inf in this problem)
  return (u16)(r>>16);
}

#define MFMA16(a,b,c) __builtin_amdgcn_mfma_f32_16x16x32_bf16(a,b,c,0,0,0)

// ---- attn LDS layout (u16 offsets). Strides 264/72: row-stride ≡ 4 banks →
// fragment reads serialize only to the 1024B/wave minimum (no net conflict).
static constexpr int XS_STR  = 264;
static constexpr int PS_STR  = 72;
static constexpr int WT_STR  = 72;
static constexpr int XHI_OFF = 0;         // 64x264
static constexpr int XLO_OFF = 16896;
static constexpr int GT_OFF  = 33792;     // 64x264, Ghi then Glo per head
static constexpr int XVT_OFF = 50688;     // 256x72, persistent Xv^T
static constexpr int PS_OFF  = 69120;     // 64x72
static constexpr int SMRE_OFF= 73728;     // 64 rows x 2 halves x (mx,sum) f32
static constexpr int SMEM_BYTES = (73728 + 512)*2;   // 148480 B

// ---- mh LDS
static constexpr int MH_SMEM = 70656*2;   // Qhi/Qlo 64x264 + Chi/Clo 256x72

// ---- ws layout (u16): mhi[524288] | mlo[524288] | khi[65536] | klo[65536]
//                       | vT[65536] | soP[4096 u16 = 2048 f32]   (~2.38 MB)

// prep: 0..63 ksplit | 64..79 vT | 80..335 so | 336..847 zero out
__global__ void prep_kernel(const float* __restrict__ k, const float* __restrict__ v,
                            const float* __restrict__ o, u16* __restrict__ khi,
                            u16* __restrict__ klo, u16* __restrict__ vT,
                            float* __restrict__ soP, float4* __restrict__ outz){
  __shared__ float Ts[64*65];
  const int blk = blockIdx.x, tid = threadIdx.x;
  if (blk < 64){
    int base = blk*1024 + tid*4;
    const float4 f4 = *(const float4*)(k + base);
    ushort4 hv, lv;
    hv.x=f2bf(f4.x); lv.x=f2bf(f4.x-bf2f(hv.x));
    hv.y=f2bf(f4.y); lv.y=f2bf(f4.y-bf2f(hv.y));
    hv.z=f2bf(f4.z); lv.z=f2bf(f4.z-bf2f(hv.z));
    hv.w=f2bf(f4.w); lv.w=f2bf(f4.w-bf2f(hv.w));
    *(ushort4*)&khi[base] = hv;
    *(ushort4*)&klo[base] = lv;
  } else if (blk < 80){
    int t = blk - 64;
    const int bi = (t>>2)<<6, bj = (t&3)<<6;
    #pragma unroll
    for (int p=0;p<4;p++){
      int idx4 = tid + (p<<8);
      int i = idx4 >> 4, c4 = (idx4 & 15) << 2;
      const float4 f4 = *(const float4*)(v + ((bi+i)<<8) + bj + c4);
      Ts[i*65+c4]=f4.x; Ts[i*65+c4+1]=f4.y; Ts[i*65+c4+2]=f4.z; Ts[i*65+c4+3]=f4.w;
    }
    __syncthreads();
    #pragma unroll
    for (int p=0;p<2;p++){
      int ch = tid + (p<<8);
      int j = ch >> 3, i8 = (ch & 7) << 3;
      short8 t8;
      #pragma unroll
      for (int e=0;e<8;e++) t8[e] = (short)f2bf(Ts[(i8+e)*65 + j]);
      *(short8*)&vT[((bj+j)<<8) + bi + i8] = t8;
    }
  } else if (blk < 336){
    int p = blk - 80;                      // 256 blocks: 8 h x 32 chunks of 8 rows
    int h = p >> 5, base = (p & 31) << 3;
    int w = tid >> 6, l = tid & 63;
    #pragma unroll
    for (int i=0;i<2;i++){
      int row = base + w*2 + i;
      const float4 f4 = *(const float4*)(o + (((h<<8)+row)<<8) + (l<<2));
      float s = f4.x + f4.y + f4.z + f4.w;
      #pragma unroll
      for (int off=32; off>=1; off>>=1) s += __shfl_xor(s, off, 64);
      if (l==0) soP[(h<<8)+row] = s;
    }
  } else {
    int z = blk - 336;                     // 512 blocks x 4096 float4
    const float4 zf4 = {0.f,0.f,0.f,0.f};
    #pragma unroll
    for (int i=0;i<16;i++) outz[z*4096 + i*256 + tid] = zf4;
  }
}

// MhT[h][dp][d] = sum_ko q[h][d][ko]*k[dp][ko], hi/lo bf16 via 3-term MFMA
__global__ __launch_bounds__(256,1) void mh_kernel(
    const float* __restrict__ q, const u16* __restrict__ khi,
    const u16* __restrict__ klo, u16* __restrict__ mhi, u16* __restrict__ mlo)
{
  extern __shared__ u16 sm[];
  u16* Qhi = sm;
  u16* Qlo = sm + 16896;
  u16* Chi = sm + 33792;
  u16* Clo = sm + 52224;

  const int tid = threadIdx.x;
  const int w = tid >> 6, lane = tid & 63;
  const int quad = lane >> 4, m16 = lane & 15;
  const int cw = w << 6, koq = quad << 3;
  const int h = blockIdx.x >> 2, dt = (blockIdx.x & 3) << 6;

  #pragma unroll
  for (int i=0;i<16;i++){
    int idx4 = i*256 + tid;
    int tr = idx4 >> 6, c4 = (idx4 & 63) << 2;
    const float4 xv = *(const float4*)(q + (((h<<8)+dt+tr)<<8) + c4);
    ushort4 hv, lv;
    hv.x=f2bf(xv.x); lv.x=f2bf(xv.x-bf2f(hv.x));
    hv.y=f2bf(xv.y); lv.y=f2bf(xv.y-bf2f(hv.y));
    hv.z=f2bf(xv.z); lv.z=f2bf(xv.z-bf2f(hv.z));
    hv.w=f2bf(xv.w); lv.w=f2bf(xv.w-bf2f(hv.w));
    *(ushort4*)&Qhi[tr*XS_STR + c4] = hv;
    *(ushort4*)&Qlo[tr*XS_STR + c4] = lv;
  }
  __syncthreads();

  const f32x4 zf = {0.f,0.f,0.f,0.f};
  f32x4 acc[4][4];
  #pragma unroll
  for (int r=0;r<4;r++)
    #pragma unroll
    for (int c=0;c<4;c++) acc[r][c] = zf;

  short8 Bh[2][4], Bl[2][4];
  #pragma unroll
  for (int c=0;c<4;c++){
    Bh[0][c] = *(const short8*)&khi[(cw + c*16 + m16)*256 + koq];
    Bl[0][c] = *(const short8*)&klo[(cw + c*16 + m16)*256 + koq];
  }
  #pragma unroll
  for (int kk=0;kk<8;kk++){
    const int cur = kk&1, nxt = cur^1;
    if (kk<7){
      const int ko2 = ((kk+1)<<5) + koq;
      #pragma unroll
      for (int c=0;c<4;c++){
        Bh[nxt][c] = *(const short8*)&khi[(cw + c*16 + m16)*256 + ko2];
        Bl[nxt][c] = *(const short8*)&klo[(cw + c*16 + m16)*256 + ko2];
      }
    }
    const int ko = (kk<<5) + koq;
    short8 Ah[4], Al[4];
    #pragma unroll
    for (int r=0;r<4;r++) Ah[r] = *(const short8*)&Qhi[(r*16+m16)*XS_STR + ko];
    #pragma unroll
    for (int r=0;r<4;r++) Al[r] = *(const short8*)&Qlo[(r*16+m16)*XS_STR + ko];
    #pragma unroll
    for (int r=0;r<4;r++)
      #pragma unroll
      for (int c=0;c<4;c++){
        acc[r][c] = MFMA16(Ah[r], Bh[cur][c], acc[r][c]);
        acc[r][c] = MFMA16(Ah[r], Bl[cur][c], acc[r][c]);
        acc[r][c] = MFMA16(Al[r], Bh[cur][c], acc[r][c]);
      }
  }

  #pragma unroll
  for (int r=0;r<4;r++)
    #pragma unroll
    for (int c=0;c<4;c++)
      #pragma unroll
      for (int g=0; g<4; g++){
        int drow = r*16 + quad*4 + g;
        int dp   = cw + c*16 + m16;
        float vv = acc[r][c][g];
        u16 hh = f2bf(vv);
        Chi[dp*WT_STR + drow] = hh;
        Clo[dp*WT_STR + drow] = f2bf(vv - bf2f(hh));
      }
  __syncthreads();

  #pragma unroll
  for (int p=0;p<8;p++){
    int ch = tid + (p<<8);
    int dp = ch >> 3, i8 = (ch & 7) << 3;
    *(int4*)&mhi[(((h<<8)+dp)<<8) + dt + i8] = *(const int4*)&Chi[dp*WT_STR + i8];
    *(int4*)&mlo[(((h<<8)+dp)<<8) + dt + i8] = *(const int4*)&Clo[dp*WT_STR + i8];
  }
}

// Merged attention: blocks [0,512) branch 0 (per-(b,y), heads 0..3),
// [512,1024) branch 1 (per-(b,x), heads 4..7). out pre-zeroed; atomicAdd.
// 8 waves: mm3/Xv/Y split 4rt x 2ct (1x global-B redundancy, dbuf prefetch);
// logits split 16-row x 32-z with B-side Xhi persisted in registers (XB).
__global__ __launch_bounds__(512,2) void attn_kernel(
    const float* __restrict__ x, const u16* __restrict__ mhiP,
    const u16* __restrict__ mloP, const u16* __restrict__ vT,
    const float* __restrict__ soP, float* __restrict__ out)
{
  extern __shared__ u16 sm[];
  u16* Xhi = sm + XHI_OFF;
  u16* Xlo = sm + XLO_OFF;
  u16* Gt  = sm + GT_OFF;
  u16* Xvt = sm + XVT_OFF;
  u16* Ps  = sm + PS_OFF;
  float* SMf = (float*)(sm + SMRE_OFF);   // [row][half][mx,sum]

  const int tid  = threadIdx.x;
  const int w    = tid >> 6, lane = tid & 63;
  const int quad = lane >> 4, m16 = lane & 15;
  const int br   = blockIdx.x >> 9;
  const int idx  = blockIdx.x & 511;
  const int b    = idx >> 6, s = idx & 63;
  const int cw   = w << 5;            // 32-col strip for mm3/Xv/Y
  const int rs   = (w >> 1) << 4;     // logits: 16-row strip
  const int zh   = w & 1;             // logits: z half (32 cols)
  const int koq  = quad << 3;

  auto tok = [&](int t)->int {
    int m = br ? s : t;
    int n = br ? t : s;
    return (((b<<6) + m) << 14) + (n << 8);
  };

  // ---- stage X hi/lo (4096 float4, 8 iters x 512 threads)
  #pragma unroll
  for (int i=0;i<8;i++){
    int idx4 = i*512 + tid;
    int tr = idx4 >> 6, c4 = (idx4 & 63) << 2;
    const float4 xv = *(const float4*)(x + tok(tr) + c4);
    ushort4 hv, lv;
    hv.x=f2bf(xv.x); lv.x=f2bf(xv.x-bf2f(hv.x));
    hv.y=f2bf(xv.y); lv.y=f2bf(xv.y-bf2f(hv.y));
    hv.z=f2bf(xv.z); lv.z=f2bf(xv.z-bf2f(hv.z));
    hv.w=f2bf(xv.w); lv.w=f2bf(xv.w-bf2f(hv.w));
    *(ushort4*)&Xhi[tr*XS_STR + c4] = hv;
    *(ushort4*)&Xlo[tr*XS_STR + c4] = lv;
  }
  __syncthreads();

  // ---- persist logits B-side Xhi fragments (constant across heads): 64 VGPRs
  short8 XB[16];
  #pragma unroll
  for (int kk=0;kk<8;kk++)
    #pragma unroll
    for (int c=0;c<2;c++)
      XB[kk*2+c] = *(const short8*)&Xhi[((zh<<5) + c*16 + m16)*XS_STR + (kk<<5) + koq];

  const f32x4 zf = {0.f,0.f,0.f,0.f};
  f32x4 acc[4][2];

  // acc = Xhi@Whi + Xhi@Wlo + Xlo@Whi over wave's 32-col strip, dbuf B-loads
  auto mm3 = [&](const u16* __restrict__ Whi, const u16* __restrict__ Wlo){
    #pragma unroll
    for (int r=0;r<4;r++){ acc[r][0] = zf; acc[r][1] = zf; }
    short8 Bh[2][2], Bl[2][2];
    #pragma unroll
    for (int c=0;c<2;c++){
      Bh[0][c] = *(const short8*)&Whi[(cw + c*16 + m16)*256 + koq];
      Bl[0][c] = *(const short8*)&Wlo[(cw + c*16 + m16)*256 + koq];
    }
    #pragma unroll
    for (int kk=0;kk<8;kk++){
      const int cur = kk&1, nxt = cur^1;
      if (kk<7){
        const int ko2 = ((kk+1)<<5) + koq;
        #pragma unroll
        for (int c=0;c<2;c++){
          Bh[nxt][c] = *(const short8*)&Whi[(cw + c*16 + m16)*256 + ko2];
          Bl[nxt][c] = *(const short8*)&Wlo[(cw + c*16 + m16)*256 + ko2];
        }
      }
      const int ko = (kk<<5) + koq;
      short8 Ah[4], Al[4];
      #pragma unroll
      for (int r=0;r<4;r++) Ah[r] = *(const short8*)&Xhi[(r*16+m16)*XS_STR + ko];
      #pragma unroll
      for (int r=0;r<4;r++) Al[r] = *(const short8*)&Xlo[(r*16+m16)*XS_STR + ko];
      #pragma unroll
      for (int r=0;r<4;r++)
        #pragma unroll
        for (int c=0;c<2;c++){
          acc[r][c] = MFMA16(Ah[r], Bh[cur][c], acc[r][c]);
          acc[r][c] = MFMA16(Ah[r], Bl[cur][c], acc[r][c]);
          acc[r][c] = MFMA16(Al[r], Bh[cur][c], acc[r][c]);
        }
    }
  };

  // ---- Xv = Xhi @ vT over wave's 32 cols; store Xv^T (unscaled) in LDS
  {
    #pragma unroll
    for (int r=0;r<4;r++){ acc[r][0] = zf; acc[r][1] = zf; }
    #pragma unroll
    for (int kk=0;kk<8;kk++){
      const int ko = (kk<<5) + koq;
      short8 A[4], Bf[2];
      #pragma unroll
      for (int r=0;r<4;r++) A[r]  = *(const short8*)&Xhi[(r*16+m16)*XS_STR + ko];
      #pragma unroll
      for (int c=0;c<2;c++) Bf[c] = *(const short8*)&vT[(cw + c*16 + m16)*256 + ko];
      #pragma unroll
      for (int r=0;r<4;r++)
        #pragma unroll
        for (int c=0;c<2;c++) acc[r][c] = MFMA16(A[r], Bf[c], acc[r][c]);
    }
    #pragma unroll
    for (int r=0;r<4;r++)
      #pragma unroll
      for (int c=0;c<2;c++)
        #pragma unroll
        for (int g=0; g<4; g++){
          int z  = r*16 + quad*4 + g;
          int vc = cw + c*16 + m16;
          Xvt[vc*WT_STR + z] = f2bf(acc[r][c][g]);
        }
    // visible after bar1 of head 0
  }

  f32x4 Z[4][2];
  #pragma unroll
  for (int r=0;r<4;r++){ Z[r][0] = zf; Z[r][1] = zf; }

  for (int h=0; h<4; h++){
    const int gh = br*4 + h;

    // ---- G = X @ Mh[gh] (3-term hi/lo); write Ghi (all rows x own 32 cols)
    mm3(mhiP + gh*65536, mloP + gh*65536);
    #pragma unroll
    for (int r=0;r<4;r++)
      #pragma unroll
      for (int c=0;c<2;c++)
        #pragma unroll
        for (int g=0; g<4; g++){
          int row = r*16 + quad*4 + g;
          int col = cw + c*16 + m16;
          Gt[row*XS_STR + col] = f2bf(acc[r][c][g]);
        }
    __syncthreads();                       // bar1: Ghi (+Xvt at h==0) visible

    // ---- logits A: Ghi@Xhi^T (regs) + Ghi@Xlo^T. Rows rs..rs+16, z half zh.
    f32x4 L[2];
    L[0] = zf; L[1] = zf;
    #pragma unroll
    for (int kk=0;kk<8;kk++){
      const int ko = (kk<<5) + koq;
      short8 A = *(const short8*)&Gt[(rs+m16)*XS_STR + ko];
      #pragma unroll
      for (int c=0;c<2;c++){
        L[c] = MFMA16(A, XB[kk*2+c], L[c]);
        short8 Bl = *(const short8*)&Xlo[((zh<<5) + c*16 + m16)*XS_STR + ko];
        L[c] = MFMA16(A, Bl, L[c]);
      }
    }
    __syncthreads();                       // bar2: Gt-hi reads done -> overwrite
    #pragma unroll
    for (int r=0;r<4;r++)
      #pragma unroll
      for (int c=0;c<2;c++)
        #pragma unroll
        for (int g=0; g<4; g++){
          int row = r*16 + quad*4 + g;
          int col = cw + c*16 + m16;
          float vv = acc[r][c][g];
          u16 hh = f2bf(vv);
          Gt[row*XS_STR + col] = f2bf(vv - bf2f(hh));   // Glo
        }
    __syncthreads();                       // bar3: Glo visible

    // ---- logits B: Glo@Xhi^T (regs)
    #pragma unroll
    for (int kk=0;kk<8;kk++){
      const int ko = (kk<<5) + koq;
      short8 A = *(const short8*)&Gt[(rs+m16)*XS_STR + ko];
      #pragma unroll
      for (int c=0;c<2;c++)
        L[c] = MFMA16(A, XB[kk*2+c], L[c]);
    }

    // ---- softmax: local (32-z half) max/sum, cross-wave merge via SMf
    float mxl[4], sml[4];
    #pragma unroll
    for (int g=0; g<4; g++){
      float mx = fmaxf(L[0][g], L[1][g]);
      #pragma unroll
      for (int off=1; off<16; off<<=1) mx = fmaxf(mx, __shfl_xor(mx, off, 64));
      float sum = 0.f;
      #pragma unroll
      for (int c=0;c<2;c++){ float e = __expf(L[c][g]-mx); L[c][g] = e; sum += e; }
      #pragma unroll
      for (int off=1; off<16; off<<=1) sum += __shfl_xor(sum, off, 64);
      mxl[g] = mx; sml[g] = sum;
      if (m16 == 0){
        int row = rs + quad*4 + g;
        SMf[row*4 + zh*2]     = mx;
        SMf[row*4 + zh*2 + 1] = sum;
      }
    }
    __syncthreads();                       // bar4: SMf visible
    #pragma unroll
    for (int g=0; g<4; g++){
      int row = rs + quad*4 + g;
      float mxo = SMf[row*4 + (zh^1)*2];
      float smo = SMf[row*4 + (zh^1)*2 + 1];
      float M   = fmaxf(mxl[g], mxo);
      float al  = __expf(mxl[g]-M), ao = __expf(mxo-M);
      float scale = al / (sml[g]*al + smo*ao);
      #pragma unroll
      for (int c=0;c<2;c++)
        Ps[row*PS_STR + (zh<<5) + c*16 + m16] = f2bf(L[c][g]*scale);
    }
    __syncthreads();                       // bar5: Ps visible

    // ---- Y = P @ Xv over wave's 32 cols; Z += so * Y
    #pragma unroll
    for (int r=0;r<4;r++){ acc[r][0] = zf; acc[r][1] = zf; }
    #pragma unroll
    for (int kk=0;kk<2;kk++){
      const int ko = (kk<<5) + koq;
      short8 A[4], Bf[2];
      #pragma unroll
      for (int r=0;r<4;r++) A[r]  = *(const short8*)&Ps[(r*16+m16)*PS_STR + ko];
      #pragma unroll
      for (int c=0;c<2;c++) Bf[c] = *(const short8*)&Xvt[(cw + c*16 + m16)*WT_STR + ko];
      #pragma unroll
      for (int r=0;r<4;r++)
        #pragma unroll
        for (int c=0;c<2;c++) acc[r][c] = MFMA16(A[r], Bf[c], acc[r][c]);
    }
    float sc[2];
    sc[0] = soP[gh*256 + cw + m16];
    sc[1] = soP[gh*256 + cw + 16 + m16];
    #pragma unroll
    for (int r=0;r<4;r++)
      #pragma unroll
      for (int c=0;c<2;c++)
        #pragma unroll
        for (int g=0; g<4; g++) Z[r][c][g] += sc[c]*acc[r][c][g];
    // no trailing barrier: next head's Gt writes precede bar1; all Gt/Ps/SMf
    // reads of head h complete before that head's bar4/bar5.
  }

  // ---- epilogue: atomic accumulate into pre-zeroed out
  #pragma unroll
  for (int r=0;r<4;r++)
    #pragma unroll
    for (int c=0;c<2;c++)
      #pragma unroll
      for (int g=0; g<4; g++){
        int t   = r*16 + quad*4 + g;
        int col = cw + c*16 + m16;
        atomicAdd(&out[tok(t) + col], Z[r][c][g]);
      }
}

extern "C" void kernel_launch(void* const* d_in, const int* in_sizes, int n_in,
                              void* d_out, int out_size, void* d_ws, size_t ws_size,
                              hipStream_t stream) {
  const float* x = (const float*)d_in[0];
  const float* q = (const float*)d_in[1];
  const float* k = (const float*)d_in[2];
  const float* v = (const float*)d_in[3];
  const float* o = (const float*)d_in[4];
  u16* ws   = (u16*)d_ws;                    // ~2.38 MB
  u16* mhi  = ws;
  u16* mlo  = ws + 524288;
  u16* khi  = ws + 1048576;
  u16* klo  = ws + 1114112;
  u16* vT   = ws + 1179648;
  float* soP = (float*)(ws + 1245184);
  float* out = (float*)d_out;

  prep_kernel<<<848, 256, 0, stream>>>(k, v, o, khi, klo, vT, soP, (float4*)d_out);
  (void)hipFuncSetAttribute(reinterpret_cast<const void*>(&mh_kernel),
                            hipFuncAttributeMaxDynamicSharedMemorySize, MH_SMEM);
  mh_kernel<<<32, 256, MH_SMEM, stream>>>(q, khi, klo, mhi, mlo);

  (void)hipFuncSetAttribute(reinterpret_cast<const void*>(&attn_kernel),
                            hipFuncAttributeMaxDynamicSharedMemorySize, SMEM_BYTES);
  attn_kernel<<<1024, 512, SMEM_BYTES, stream>>>(x, mhi, mlo, vT, soP, out);
}